// Round 1
// baseline (1769.798 us; speedup 1.0000x reference)
//
#include <hip/hip_runtime.h>
#include <hip/hip_bf16.h>
#include <float.h>

// Problem constants
#define NPIX   32768      // B*H*W
#define CDIM   128
#define KCB    8192
#define TAU    0.2f
#define RCAP   8192

// ws layout (bytes)
#define WS_Z       0                 // 32768*128 f32 = 16,777,216
#define WS_E2      16777216          // 8192 f32
#define WS_IDX     16809984          // 32768 i32
#define WS_RLIST   16941056          // 8192 * 4 i32
#define WS_COUNTS  17072128          // 8192 f32
#define WS_LOSS    17104896          // 1 f32
#define WS_RCNT    17104900          // 1 i32
// zero region: counts + loss + rcnt
#define WS_ZERO_OFF 17072128
#define WS_ZERO_LEN 32776

// d_out layout (f32 elements): [0]=loss, [1..4194304]=out BCHW, [4194305]=perplexity, [4194306..]=idx
#define OUT_OFF_OUT  1
#define OUT_OFF_PERP 4194305
#define OUT_OFF_IDX  4194306

__device__ __forceinline__ void addcand(float v, int idx, float& m1, int& i1, float& m2, int& i2) {
    if (v < m1 || (v == m1 && idx < i1)) { m2 = m1; i2 = i1; m1 = v; i1 = idx; }
    else if (v < m2 || (v == m2 && idx < i2)) { m2 = v; i2 = idx; }
}

// ---------------- K0: e2[k] = sum_c emb[k][c]^2 ----------------
__global__ __launch_bounds__(256) void k_e2(const float* __restrict__ emb, float* __restrict__ e2) {
    int t = threadIdx.x;
    int wv = t >> 6, l = t & 63;
    int k = blockIdx.x * 4 + wv;
    const float2 v = *(const float2*)&emb[(size_t)k * 128 + l * 2];
    float s = v.x * v.x + v.y * v.y;
    #pragma unroll
    for (int o = 32; o; o >>= 1) s += __shfl_down(s, o, 64);
    if (l == 0) e2[k] = s;
}

// ---------------- K2: fused linear + distance + top2 argmin ----------------
// grid 512 blocks x 256 threads; each block: 64 pixels, full K=8192.
__global__ __launch_bounds__(256, 2) void k_main(
    const float* __restrict__ x, const float* __restrict__ Wl, const float* __restrict__ bl,
    const float* __restrict__ emb, const float* __restrict__ e2,
    float* __restrict__ zws, int* __restrict__ idxws,
    int* __restrict__ rlist, int* __restrict__ rcnt,
    float* __restrict__ out_idxf)
{
    __shared__ __align__(16) float As[128 * 64];   // z-tile, layout [c][n]  (32 KB)
    __shared__ __align__(16) float Bs[8192];       // union: X-stage / emb-chunk / merge buf (32 KB)

    const int t  = threadIdx.x;
    const int n0 = blockIdx.x * 64;
    const int b  = n0 >> 10;          // batch index (64-tiles never cross batch)
    const int hw0 = n0 & 1023;

    // ===== Phase 1: z for 64 pixels (z[p][i] = b[i] + sum_c W[i][c] x[b][c][p]) =====
    {
        const int p = t & 63, ig = t >> 6;
        float accz[32];
        const float4* bl4 = (const float4*)(bl + ig * 32);
        #pragma unroll
        for (int q = 0; q < 8; ++q) {
            float4 v = bl4[q];
            accz[4*q+0] = v.x; accz[4*q+1] = v.y; accz[4*q+2] = v.z; accz[4*q+3] = v.w;
        }
        for (int half = 0; half < 2; ++half) {
            __syncthreads();
            // stage X[cc=0..64][p=0..64] (c = half*64+cc) into Bs with stride 66
            for (int r = 0; r < 16; ++r) {
                int lin = r * 256 + t;
                int cc = lin >> 6, pp = lin & 63;
                Bs[cc * 66 + pp] = x[(size_t)(b * 128 + half * 64 + cc) * 1024 + hw0 + pp];
            }
            __syncthreads();
            for (int cc4 = 0; cc4 < 16; ++cc4) {
                float xv0 = Bs[(cc4*4+0) * 66 + p];
                float xv1 = Bs[(cc4*4+1) * 66 + p];
                float xv2 = Bs[(cc4*4+2) * 66 + p];
                float xv3 = Bs[(cc4*4+3) * 66 + p];
                #pragma unroll
                for (int ii = 0; ii < 32; ++ii) {
                    const float4 w4 = *(const float4*)&Wl[(size_t)(ig*32+ii) * 128 + half*64 + cc4*4];
                    float a = accz[ii];
                    a = fmaf(w4.x, xv0, a);
                    a = fmaf(w4.y, xv1, a);
                    a = fmaf(w4.z, xv2, a);
                    a = fmaf(w4.w, xv3, a);
                    accz[ii] = a;
                }
            }
        }
        // write z into As [i][p] (A operand, layout [c][n]) and to global ws
        #pragma unroll
        for (int ii = 0; ii < 32; ++ii) As[(ig*32+ii) * 64 + p] = accz[ii];
        float4* zo = (float4*)(zws + (size_t)(n0 + p) * 128 + ig * 32);
        #pragma unroll
        for (int q = 0; q < 8; ++q)
            zo[q] = make_float4(accz[4*q+0], accz[4*q+1], accz[4*q+2], accz[4*q+3]);
    }

    // ===== Phase 2: distance GEMM + top-2 over K =====
    const int tn = t & 7;     // n-group: n = n0 + tn*8 + i
    const int tk = t >> 3;    // k-group: k = k0 + tk*8 + j  (tk in [0,32))
    float m1[8], m2[8]; int i1[8], i2[8];
    #pragma unroll
    for (int i = 0; i < 8; ++i) { m1[i] = 3e38f; m2[i] = 3e38f; i1[i] = 0; i2[i] = 0; }

    for (int k0 = 0; k0 < KCB; k0 += 256) {
        float acc[8][8];
        #pragma unroll
        for (int i = 0; i < 8; ++i)
            #pragma unroll
            for (int j = 0; j < 8; ++j) acc[i][j] = 0.f;

        for (int ch = 0; ch < 4; ++ch) {
            __syncthreads();
            // stage emb[k0+kk][ch*32 .. +32] -> Bs[c][256]
            {
                int kk0 = t >> 3, c4 = t & 7;
                for (int r = 0; r < 8; ++r) {
                    int kk = r * 32 + kk0;
                    const float4 v = *(const float4*)&emb[(size_t)(k0 + kk) * 128 + ch * 32 + c4 * 4];
                    Bs[(c4*4+0) * 256 + kk] = v.x;
                    Bs[(c4*4+1) * 256 + kk] = v.y;
                    Bs[(c4*4+2) * 256 + kk] = v.z;
                    Bs[(c4*4+3) * 256 + kk] = v.w;
                }
            }
            __syncthreads();
            #pragma unroll 8
            for (int c = 0; c < 32; ++c) {
                const float4 a0 = *(const float4*)&As[(ch*32+c) * 64 + tn*8];
                const float4 a1 = *(const float4*)&As[(ch*32+c) * 64 + tn*8 + 4];
                const float4 b0 = *(const float4*)&Bs[c * 256 + tk*8];
                const float4 b1 = *(const float4*)&Bs[c * 256 + tk*8 + 4];
                float av[8] = {a0.x,a0.y,a0.z,a0.w,a1.x,a1.y,a1.z,a1.w};
                float bv[8] = {b0.x,b0.y,b0.z,b0.w,b1.x,b1.y,b1.z,b1.w};
                #pragma unroll
                for (int i = 0; i < 8; ++i)
                    #pragma unroll
                    for (int j = 0; j < 8; ++j)
                        acc[i][j] = fmaf(av[i], bv[j], acc[i][j]);
            }
        }
        // m = e2[k] - 2*acc  (||z||^2 dropped: constant per row)
        const float4 e20 = *(const float4*)&e2[k0 + tk*8];
        const float4 e21 = *(const float4*)&e2[k0 + tk*8 + 4];
        float e2v[8] = {e20.x,e20.y,e20.z,e20.w,e21.x,e21.y,e21.z,e21.w};
        #pragma unroll
        for (int j = 0; j < 8; ++j) {
            int kk = k0 + tk*8 + j;
            #pragma unroll
            for (int i = 0; i < 8; ++i) {
                float m = fmaf(-2.f, acc[i][j], e2v[j]);
                addcand(m, kk, m1[i], i1[i], m2[i], i2[i]);
            }
        }
    }

    // ===== Phase 3: cross-thread merge (32 tk-lists per n) =====
    __syncthreads();
    float4* Ms = (float4*)Bs;     // [64 n][32 tk]
    #pragma unroll
    for (int i = 0; i < 8; ++i)
        Ms[(tn*8+i) * 32 + tk] = make_float4(m1[i], __int_as_float(i1[i]), m2[i], __int_as_float(i2[i]));
    __syncthreads();
    if (t < 64) {
        int n = n0 + t;
        float g1 = 3e38f, g2 = 3e38f; int j1 = 0, j2 = 0;
        for (int w = 0; w < 32; ++w) {
            float4 e = Ms[t * 32 + w];
            addcand(e.x, __float_as_int(e.y), g1, j1, g2, j2);
            addcand(e.z, __float_as_int(e.w), g1, j1, g2, j2);
        }
        idxws[n] = j1;
        out_idxf[n] = (float)j1;
        if (g2 - g1 < TAU) {
            int s = atomicAdd(rcnt, 1);
            if (s < RCAP) { rlist[s*4+0] = n; rlist[s*4+1] = j1; rlist[s*4+2] = j2; }
        }
    }
}

// ---------------- K3: fp64 refinement of near-ties ----------------
__global__ __launch_bounds__(128) void k_refine(
    const float* __restrict__ x, const float* __restrict__ Wl, const float* __restrict__ bl,
    const float* __restrict__ emb, const int* __restrict__ rcnt, const int* __restrict__ rlist,
    int* __restrict__ idxws, float* __restrict__ out_idxf)
{
    __shared__ double xs[128];
    __shared__ double red[128];
    int cnt = *rcnt; if (cnt > RCAP) cnt = RCAP;
    const int t = threadIdx.x;
    for (int e = blockIdx.x; e < cnt; e += gridDim.x) {
        int n  = rlist[e*4+0];
        int c1 = rlist[e*4+1];
        int c2 = rlist[e*4+2];
        int b = n >> 10, hw = n & 1023;
        __syncthreads();
        xs[t] = (double)x[(size_t)(b * 128 + t) * 1024 + hw];
        __syncthreads();
        double z = (double)bl[t];
        for (int c = 0; c < 128; ++c) z += (double)Wl[(size_t)t * 128 + c] * xs[c];
        double d1, d2;
        {
            double da = z - (double)emb[(size_t)c1 * 128 + t];
            red[t] = da * da; __syncthreads();
            for (int o = 64; o; o >>= 1) { if (t < o) red[t] += red[t + o]; __syncthreads(); }
            d1 = red[0]; __syncthreads();
            double db = z - (double)emb[(size_t)c2 * 128 + t];
            red[t] = db * db; __syncthreads();
            for (int o = 64; o; o >>= 1) { if (t < o) red[t] += red[t + o]; __syncthreads(); }
            d2 = red[0];
        }
        if (t == 0) {
            int win = (d2 < d1 || (d2 == d1 && c2 < c1)) ? c2 : c1;
            idxws[n] = win;
            out_idxf[n] = (float)win;
        }
        __syncthreads();
    }
}

// ---------------- K4: gather + transpose + loss partial + histogram ----------------
__global__ __launch_bounds__(256) void k_out(
    const float* __restrict__ zws, const float* __restrict__ emb, const int* __restrict__ idxws,
    float* __restrict__ outp /* d_out + 1 */, float* __restrict__ losssum, float* __restrict__ counts)
{
    __shared__ __align__(16) float Zs[32 * 132];
    __shared__ int is[32];
    const int bid = blockIdx.x;          // 0..1023
    const int b = bid >> 5, h = bid & 31;
    const int nb = b * 1024 + h * 32;
    const int t = threadIdx.x;
    for (int r = 0; r < 4; ++r) {
        int lin = r * 256 + t;
        int w = lin >> 5, c4 = lin & 31;
        const float4 v = *(const float4*)&zws[(size_t)(nb + w) * 128 + c4 * 4];
        Zs[w * 132 + c4*4 + 0] = v.x; Zs[w * 132 + c4*4 + 1] = v.y;
        Zs[w * 132 + c4*4 + 2] = v.z; Zs[w * 132 + c4*4 + 3] = v.w;
    }
    if (t < 32) is[t] = idxws[nb + t];
    __syncthreads();
    const int w = t & 31, cg = t >> 5;
    const int id = is[w];
    float ls = 0.f;
    #pragma unroll
    for (int cc4 = 0; cc4 < 4; ++cc4) {
        int c = cg * 16 + cc4 * 4;
        const float4 z4 = *(const float4*)&Zs[w * 132 + c];
        const float4 q4 = *(const float4*)&emb[(size_t)id * 128 + c];
        float zz[4] = {z4.x, z4.y, z4.z, z4.w};
        float qq[4] = {q4.x, q4.y, q4.z, q4.w};
        #pragma unroll
        for (int q = 0; q < 4; ++q) {
            float v = zz[q] + (qq[q] - zz[q]);                 // straight-through forward
            outp[((size_t)(b * 128 + c + q) * 32 + h) * 32 + w] = v;
            float d = qq[q] - zz[q];
            ls = fmaf(d, d, ls);
        }
    }
    #pragma unroll
    for (int o = 32; o; o >>= 1) ls += __shfl_down(ls, o, 64);
    __shared__ float wred[4];
    if ((t & 63) == 0) wred[t >> 6] = ls;
    __syncthreads();
    if (t == 0) atomicAdd(losssum, wred[0] + wred[1] + wred[2] + wred[3]);
    if (t < 32) atomicAdd(&counts[is[t]], 1.0f);
}

// ---------------- K5: finalize loss + perplexity ----------------
__global__ __launch_bounds__(256) void k_final(
    const float* __restrict__ counts, const float* __restrict__ losssum, float* __restrict__ d_out)
{
    const int t = threadIdx.x;
    float ent = 0.f;
    for (int k = t; k < KCB; k += 256) {
        float p = counts[k] * (1.0f / 32768.0f);
        ent -= p * logf(p + 1e-10f);
    }
    #pragma unroll
    for (int o = 32; o; o >>= 1) ent += __shfl_down(ent, o, 64);
    __shared__ float wred[4];
    if ((t & 63) == 0) wred[t >> 6] = ent;
    __syncthreads();
    if (t == 0) {
        float e = wred[0] + wred[1] + wred[2] + wred[3];
        d_out[0] = 1.25f * (*losssum) * (1.0f / 4194304.0f);
        d_out[OUT_OFF_PERP] = expf(e);
    }
}

extern "C" void kernel_launch(void* const* d_in, const int* in_sizes, int n_in,
                              void* d_out, int out_size, void* d_ws, size_t ws_size,
                              hipStream_t stream) {
    (void)in_sizes; (void)n_in; (void)out_size; (void)ws_size;
    const float* x   = (const float*)d_in[0];
    const float* Wl  = (const float*)d_in[1];
    const float* bl  = (const float*)d_in[2];
    const float* emb = (const float*)d_in[3];
    float* out = (float*)d_out;
    char*  ws  = (char*)d_ws;

    float* zws     = (float*)(ws + WS_Z);
    float* e2      = (float*)(ws + WS_E2);
    int*   idxws   = (int*)  (ws + WS_IDX);
    int*   rlist   = (int*)  (ws + WS_RLIST);
    float* counts  = (float*)(ws + WS_COUNTS);
    float* losssum = (float*)(ws + WS_LOSS);
    int*   rcnt    = (int*)  (ws + WS_RCNT);

    hipMemsetAsync(ws + WS_ZERO_OFF, 0, WS_ZERO_LEN, stream);

    k_e2<<<KCB / 4, 256, 0, stream>>>(emb, e2);
    k_main<<<NPIX / 64, 256, 0, stream>>>(x, Wl, bl, emb, e2, zws, idxws, rlist, rcnt,
                                          out + OUT_OFF_IDX);
    k_refine<<<128, 128, 0, stream>>>(x, Wl, bl, emb, rcnt, rlist, idxws, out + OUT_OFF_IDX);
    k_out<<<1024, 256, 0, stream>>>(zws, emb, idxws, out + OUT_OFF_OUT, losssum, counts);
    k_final<<<1, 256, 0, stream>>>(counts, losssum, out);
}

// Round 2
// 453.743 us; speedup vs baseline: 3.9004x; 3.9004x over previous
//
#include <hip/hip_runtime.h>
#include <hip/hip_bf16.h>
#include <float.h>

// Problem constants
#define NPIX   32768      // B*H*W
#define CDIM   128
#define KCB    8192
#define TAU    0.02f
#define RCAP   8192

typedef _Float16 f16x8 __attribute__((ext_vector_type(8)));
typedef float    f32x16 __attribute__((ext_vector_type(16)));

// ws layout (bytes)
// embF: 256 tiles x 9 steps x 64 lanes x 8 halves = 1,179,648 f16 = 2,359,296 B per split
#define WS_EMBFH   0
#define WS_EMBFL   2359296
#define WS_E2      4718592           // 8192 f32
#define WS_IDX     4751360           // 32768 i32
#define WS_RLIST   4882432           // 8192*4 i32
#define WS_COUNTS  5013504           // 8192 f32
#define WS_LOSS    5046272           // 1 f32
#define WS_RCNT    5046276           // 1 i32
#define WS_ZERO_OFF 5013504
#define WS_ZERO_LEN 32776

// d_out layout (f32): [0]=loss, [1..4194304]=out BCHW, [4194305]=perplexity, [4194306..]=idx
#define OUT_OFF_OUT  1
#define OUT_OFF_PERP 4194305
#define OUT_OFF_IDX  4194306

__device__ __forceinline__ void addcand(float v, int idx, float& m1, int& i1, float& m2, int& i2) {
    if (v < m1 || (v == m1 && idx < i1)) { m2 = m1; i2 = i1; m1 = v; i1 = idx; }
    else if (v < m2 || (v == m2 && idx < i2)) { m2 = v; i2 = idx; }
}

// ---------------- K0: e2[k] = sum_c emb[k][c]^2 ----------------
__global__ __launch_bounds__(256) void k_e2(const float* __restrict__ emb, float* __restrict__ e2) {
    int t = threadIdx.x;
    int wv = t >> 6, l = t & 63;
    int k = blockIdx.x * 4 + wv;
    const float2 v = *(const float2*)&emb[(size_t)k * 128 + l * 2];
    float s = v.x * v.x + v.y * v.y;
    #pragma unroll
    for (int o = 32; o; o >>= 1) s += __shfl_down(s, o, 64);
    if (l == 0) e2[k] = s;
}

// ---------------- K1: build fragment-ordered -2*emb in f16 hi/lo, with e2/1.0 fold ----------------
// element (g,s,lane,j): code m = g*32 + (lane&31), k-slot = s*16 + (lane>>5)*8 + j
// s<8: value = -2*emb[m][kslot]; s==8: slot128 = e2[m] (hi/lo), slot129: Ah=1.0, rest 0.
__global__ __launch_bounds__(256) void k_prep(const float* __restrict__ emb, const float* __restrict__ e2,
                                              _Float16* __restrict__ embFh, _Float16* __restrict__ embFl) {
    int tid = blockIdx.x * 256 + threadIdx.x;   // < 147456 = 8192*18
    int m = tid / 18, r = tid % 18;
    int s = r >> 1, h = r & 1;
    f16x8 hv; f16x8 lv;
    #pragma unroll
    for (int j = 0; j < 8; ++j) { hv[j] = (_Float16)0.0f; lv[j] = (_Float16)0.0f; }
    if (s < 8) {
        int c0 = s * 16 + h * 8;
        const float4 a = *(const float4*)&emb[(size_t)m * 128 + c0];
        const float4 b = *(const float4*)&emb[(size_t)m * 128 + c0 + 4];
        float vals[8] = {a.x, a.y, a.z, a.w, b.x, b.y, b.z, b.w};
        #pragma unroll
        for (int j = 0; j < 8; ++j) {
            float e = -2.0f * vals[j];
            _Float16 eh = (_Float16)e;
            hv[j] = eh;
            lv[j] = (_Float16)(e - (float)eh);
        }
    } else if (h == 0) {
        float v = e2[m];
        _Float16 eh = (_Float16)v;
        hv[0] = eh; lv[0] = (_Float16)(v - (float)eh);
        hv[1] = (_Float16)1.0f;   // slot 129: picks up z2 from B
    }
    size_t base = (((size_t)(m >> 5) * 9 + s) * 64 + (m & 31) + h * 32) * 8;
    *(f16x8*)&embFh[base] = hv;
    *(f16x8*)&embFl[base] = lv;
}

// ---------------- K2: fused linear + MFMA distance + top2 argmin ----------------
// 512 blocks x 256 thr. Block: 64 pixels. Wave w: code-tiles g = w, w+4, ... (x2 pixel N-tiles).
__global__ __launch_bounds__(256, 2) void k_main(
    const float* __restrict__ x, const float* __restrict__ Wl, const float* __restrict__ bl,
    const _Float16* __restrict__ embFh, const _Float16* __restrict__ embFl,
    int* __restrict__ idxws, int* __restrict__ rlist, int* __restrict__ rcnt,
    float* __restrict__ losssum, float* __restrict__ out_idxf)
{
    __shared__ __align__(16) float As[64 * 132];   // z [p][c], pitch 132 (33.8 KB)
    __shared__ __align__(16) float Xs[64 * 66];    // x staging / final-merge scratch (16.9 KB)

    const int t  = threadIdx.x;
    const int n0 = blockIdx.x * 64;
    const int b  = n0 >> 10;
    const int hw0 = n0 & 1023;

    // ===== Phase 1: z for 64 pixels =====
    {
        const int p = t & 63, ig = t >> 6;
        float accz[32];
        const float4* bl4 = (const float4*)(bl + ig * 32);
        #pragma unroll
        for (int q = 0; q < 8; ++q) {
            float4 v = bl4[q];
            accz[4*q+0] = v.x; accz[4*q+1] = v.y; accz[4*q+2] = v.z; accz[4*q+3] = v.w;
        }
        for (int half = 0; half < 2; ++half) {
            __syncthreads();
            for (int r = 0; r < 16; ++r) {
                int lin = r * 256 + t;
                int cc = lin >> 6, pp = lin & 63;
                Xs[cc * 66 + pp] = x[(size_t)(b * 128 + half * 64 + cc) * 1024 + hw0 + pp];
            }
            __syncthreads();
            for (int cc4 = 0; cc4 < 16; ++cc4) {
                float xv0 = Xs[(cc4*4+0) * 66 + p];
                float xv1 = Xs[(cc4*4+1) * 66 + p];
                float xv2 = Xs[(cc4*4+2) * 66 + p];
                float xv3 = Xs[(cc4*4+3) * 66 + p];
                #pragma unroll
                for (int ii = 0; ii < 32; ++ii) {
                    const float4 w4 = *(const float4*)&Wl[(size_t)(ig*32+ii) * 128 + half*64 + cc4*4];
                    float a = accz[ii];
                    a = fmaf(w4.x, xv0, a);
                    a = fmaf(w4.y, xv1, a);
                    a = fmaf(w4.z, xv2, a);
                    a = fmaf(w4.w, xv3, a);
                    accz[ii] = a;
                }
            }
        }
        float4* ao = (float4*)&As[p * 132 + ig * 32];
        #pragma unroll
        for (int q = 0; q < 8; ++q)
            ao[q] = make_float4(accz[4*q+0], accz[4*q+1], accz[4*q+2], accz[4*q+3]);
    }
    __syncthreads();

    // ===== Phase 2: B fragments (z split f16 hi/lo) + z2 fold, in registers =====
    const int l = t & 63, w = t >> 6;
    const int half = l >> 5, pcol = l & 31;
    f16x8 Bh0[9], Bl0[9], Bh1[9], Bl1[9];
    {
        #pragma unroll
        for (int nt = 0; nt < 2; ++nt) {
            int p = nt * 32 + pcol;
            float s2 = 0.f;
            #pragma unroll
            for (int s = 0; s < 8; ++s) {
                const float* zp = &As[p * 132 + s * 16 + half * 8];
                float4 v0 = *(const float4*)zp;
                float4 v1 = *(const float4*)(zp + 4);
                float vals[8] = {v0.x, v0.y, v0.z, v0.w, v1.x, v1.y, v1.z, v1.w};
                f16x8 hh, ll;
                #pragma unroll
                for (int j = 0; j < 8; ++j) {
                    _Float16 e = (_Float16)vals[j];
                    hh[j] = e;
                    ll[j] = (_Float16)(vals[j] - (float)e);
                    s2 = fmaf(vals[j], vals[j], s2);
                }
                if (nt == 0) { Bh0[s] = hh; Bl0[s] = ll; }
                else         { Bh1[s] = hh; Bl1[s] = ll; }
            }
            float s2full = s2 + __shfl_xor(s2, 32, 64);
            _Float16 z2h = (_Float16)s2full;
            _Float16 z2l = (_Float16)(s2full - (float)z2h);
            f16x8 bh8, bl8;
            #pragma unroll
            for (int j = 0; j < 8; ++j) { bh8[j] = (_Float16)0.0f; bl8[j] = (_Float16)0.0f; }
            if (half == 0) {
                bh8[0] = (_Float16)1.0f;  // slot128: picks up e2 from A
                bh8[1] = z2h;             // slot129: A=1.0 -> z2h
                bl8[1] = z2l;             //          Ah*Bl -> z2l
            }
            if (nt == 0) { Bh0[8] = bh8; Bl0[8] = bl8; }
            else         { Bh1[8] = bh8; Bl1[8] = bl8; }
        }
    }

    // ===== Phase 3: K-loop over code tiles (no barriers, A direct from L2) =====
    float gm1[2] = {3e38f, 3e38f}, gm2[2] = {3e38f, 3e38f};
    int   gi1[2] = {0, 0},          gi2[2] = {0, 0};
    const f16x8* Ahp = (const f16x8*)embFh;
    const f16x8* Alp = (const f16x8*)embFl;
    const int rb4 = half * 4;

    for (int g = w; g < 256; g += 4) {
        f32x16 acc0 = {}; f32x16 acc1 = {};
        const f16x8* Ap = Ahp + (size_t)g * 9 * 64 + l;
        const f16x8* Lp = Alp + (size_t)g * 9 * 64 + l;
        f16x8 ah = Ap[0], al = Lp[0];
        #pragma unroll
        for (int s = 0; s < 9; ++s) {
            f16x8 ahn, aln;
            if (s < 8) { ahn = Ap[(s + 1) * 64]; aln = Lp[(s + 1) * 64]; }
            acc0 = __builtin_amdgcn_mfma_f32_32x32x16_f16(ah, Bh0[s], acc0, 0, 0, 0);
            acc1 = __builtin_amdgcn_mfma_f32_32x32x16_f16(ah, Bh1[s], acc1, 0, 0, 0);
            acc0 = __builtin_amdgcn_mfma_f32_32x32x16_f16(ah, Bl0[s], acc0, 0, 0, 0);
            acc1 = __builtin_amdgcn_mfma_f32_32x32x16_f16(ah, Bl1[s], acc1, 0, 0, 0);
            acc0 = __builtin_amdgcn_mfma_f32_32x32x16_f16(al, Bh0[s], acc0, 0, 0, 0);
            acc1 = __builtin_amdgcn_mfma_f32_32x32x16_f16(al, Bh1[s], acc1, 0, 0, 0);
            if (s < 8) { ah = ahn; al = aln; }
        }
        // packed top-2 (distance >= 0; clear low 5 mantissa bits, OR in row idx)
        float cm1a = 3e38f, cm2a = 3e38f, cm1b = 3e38f, cm2b = 3e38f;
        #pragma unroll
        for (int r = 0; r < 16; ++r) {
            const int rowc = (r & 3) + 8 * (r >> 2);
            float p0 = __uint_as_float((__float_as_uint(acc0[r]) & 0xFFFFFFE0u) | (uint32_t)(rowc + rb4));
            float mxa = fmaxf(cm1a, p0); cm1a = fminf(cm1a, p0); cm2a = fminf(cm2a, mxa);
            float p1 = __uint_as_float((__float_as_uint(acc1[r]) & 0xFFFFFFE0u) | (uint32_t)(rowc + rb4));
            float mxb = fmaxf(cm1b, p1); cm1b = fminf(cm1b, p1); cm2b = fminf(cm2b, mxb);
        }
        // merge tile-local -> global (value = bits&~31, idx = g*32 + (bits&31))
        {
            uint32_t u;
            u = __float_as_uint(cm1a); addcand(__uint_as_float(u & 0xFFFFFFE0u), g*32 + (int)(u & 31u), gm1[0], gi1[0], gm2[0], gi2[0]);
            u = __float_as_uint(cm2a); addcand(__uint_as_float(u & 0xFFFFFFE0u), g*32 + (int)(u & 31u), gm1[0], gi1[0], gm2[0], gi2[0]);
            u = __float_as_uint(cm1b); addcand(__uint_as_float(u & 0xFFFFFFE0u), g*32 + (int)(u & 31u), gm1[1], gi1[1], gm2[1], gi2[1]);
            u = __float_as_uint(cm2b); addcand(__uint_as_float(u & 0xFFFFFFE0u), g*32 + (int)(u & 31u), gm1[1], gi1[1], gm2[1], gi2[1]);
        }
    }

    // ===== Phase 4: cross-wave merge per pixel =====
    __syncthreads();
    float4* Ms = (float4*)Xs;   // [64 px][8 slots]
    const int slot = w * 2 + half;
    Ms[pcol * 8 + slot]        = make_float4(gm1[0], __int_as_float(gi1[0]), gm2[0], __int_as_float(gi2[0]));
    Ms[(32 + pcol) * 8 + slot] = make_float4(gm1[1], __int_as_float(gi1[1]), gm2[1], __int_as_float(gi2[1]));
    __syncthreads();
    if (t < 64) {
        int n = n0 + t;
        float g1 = 3e38f, g2 = 3e38f; int j1 = 0, j2 = 0;
        #pragma unroll
        for (int s = 0; s < 8; ++s) {
            float4 e = Ms[t * 8 + s];
            addcand(e.x, __float_as_int(e.y), g1, j1, g2, j2);
            addcand(e.z, __float_as_int(e.w), g1, j1, g2, j2);
        }
        idxws[n] = j1;
        out_idxf[n] = (float)j1;
        if (g2 - g1 < TAU) {
            int s = atomicAdd(rcnt, 1);
            if (s < RCAP) { rlist[s*4+0] = n; rlist[s*4+1] = j1; rlist[s*4+2] = j2; }
        }
        // loss: sum of min distances (loss = 1.25 * mean((q-z)^2) = 1.25/(N*C) * sum d_min)
        float ls = g1;
        #pragma unroll
        for (int o = 32; o; o >>= 1) ls += __shfl_down(ls, o, 64);
        if (t == 0) atomicAdd(losssum, ls);
    }
}

// ---------------- K3: fp64 refinement of near-ties ----------------
__global__ __launch_bounds__(128) void k_refine(
    const float* __restrict__ x, const float* __restrict__ Wl, const float* __restrict__ bl,
    const float* __restrict__ emb, const int* __restrict__ rcnt, const int* __restrict__ rlist,
    int* __restrict__ idxws, float* __restrict__ out_idxf)
{
    __shared__ double xs[128];
    __shared__ double red[128];
    int cnt = *rcnt; if (cnt > RCAP) cnt = RCAP;
    const int t = threadIdx.x;
    for (int e = blockIdx.x; e < cnt; e += gridDim.x) {
        int n  = rlist[e*4+0];
        int c1 = rlist[e*4+1];
        int c2 = rlist[e*4+2];
        int b = n >> 10, hw = n & 1023;
        __syncthreads();
        xs[t] = (double)x[(size_t)(b * 128 + t) * 1024 + hw];
        __syncthreads();
        double z = (double)bl[t];
        for (int c = 0; c < 128; ++c) z += (double)Wl[(size_t)t * 128 + c] * xs[c];
        double d1, d2;
        {
            double da = z - (double)emb[(size_t)c1 * 128 + t];
            red[t] = da * da; __syncthreads();
            for (int o = 64; o; o >>= 1) { if (t < o) red[t] += red[t + o]; __syncthreads(); }
            d1 = red[0]; __syncthreads();
            double db = z - (double)emb[(size_t)c2 * 128 + t];
            red[t] = db * db; __syncthreads();
            for (int o = 64; o; o >>= 1) { if (t < o) red[t] += red[t + o]; __syncthreads(); }
            d2 = red[0];
        }
        if (t == 0) {
            int win = (d2 < d1 || (d2 == d1 && c2 < c1)) ? c2 : c1;
            idxws[n] = win;
            out_idxf[n] = (float)win;
        }
        __syncthreads();
    }
}

// ---------------- K4: gather + transpose (out == quantized exactly) + histogram ----------------
__global__ __launch_bounds__(256) void k_out(
    const float* __restrict__ emb, const int* __restrict__ idxws,
    float* __restrict__ outp /* d_out + 1 */, float* __restrict__ counts)
{
    __shared__ int is[32];
    const int bid = blockIdx.x;          // 0..1023
    const int b = bid >> 5, h = bid & 31;
    const int nb = b * 1024 + h * 32;
    const int t = threadIdx.x;
    if (t < 32) is[t] = idxws[nb + t];
    __syncthreads();
    const int wcol = t & 31, cg = t >> 5;
    const int id = is[wcol];
    #pragma unroll
    for (int q = 0; q < 4; ++q) {
        int c = cg * 16 + q * 4;
        const float4 v = *(const float4*)&emb[(size_t)id * 128 + c];
        outp[((size_t)(b * 128 + c + 0) * 32 + h) * 32 + wcol] = v.x;
        outp[((size_t)(b * 128 + c + 1) * 32 + h) * 32 + wcol] = v.y;
        outp[((size_t)(b * 128 + c + 2) * 32 + h) * 32 + wcol] = v.z;
        outp[((size_t)(b * 128 + c + 3) * 32 + h) * 32 + wcol] = v.w;
    }
    if (t < 32) atomicAdd(&counts[is[t]], 1.0f);
}

// ---------------- K5: finalize loss + perplexity ----------------
__global__ __launch_bounds__(256) void k_final(
    const float* __restrict__ counts, const float* __restrict__ losssum, float* __restrict__ d_out)
{
    const int t = threadIdx.x;
    float ent = 0.f;
    for (int k = t; k < KCB; k += 256) {
        float p = counts[k] * (1.0f / 32768.0f);
        ent -= p * logf(p + 1e-10f);
    }
    #pragma unroll
    for (int o = 32; o; o >>= 1) ent += __shfl_down(ent, o, 64);
    __shared__ float wred[4];
    if ((t & 63) == 0) wred[t >> 6] = ent;
    __syncthreads();
    if (t == 0) {
        float e = wred[0] + wred[1] + wred[2] + wred[3];
        d_out[0] = 1.25f * (*losssum) * (1.0f / 4194304.0f);
        d_out[OUT_OFF_PERP] = expf(e);
    }
}

extern "C" void kernel_launch(void* const* d_in, const int* in_sizes, int n_in,
                              void* d_out, int out_size, void* d_ws, size_t ws_size,
                              hipStream_t stream) {
    (void)in_sizes; (void)n_in; (void)out_size; (void)ws_size;
    const float* x   = (const float*)d_in[0];
    const float* Wl  = (const float*)d_in[1];
    const float* bl  = (const float*)d_in[2];
    const float* emb = (const float*)d_in[3];
    float* out = (float*)d_out;
    char*  ws  = (char*)d_ws;

    _Float16* embFh = (_Float16*)(ws + WS_EMBFH);
    _Float16* embFl = (_Float16*)(ws + WS_EMBFL);
    float* e2      = (float*)(ws + WS_E2);
    int*   idxws   = (int*)  (ws + WS_IDX);
    int*   rlist   = (int*)  (ws + WS_RLIST);
    float* counts  = (float*)(ws + WS_COUNTS);
    float* losssum = (float*)(ws + WS_LOSS);
    int*   rcnt    = (int*)  (ws + WS_RCNT);

    hipMemsetAsync(ws + WS_ZERO_OFF, 0, WS_ZERO_LEN, stream);

    k_e2<<<KCB / 4, 256, 0, stream>>>(emb, e2);
    k_prep<<<576, 256, 0, stream>>>(emb, e2, embFh, embFl);
    k_main<<<NPIX / 64, 256, 0, stream>>>(x, Wl, bl, embFh, embFl,
                                          idxws, rlist, rcnt, losssum, out + OUT_OFF_IDX);
    k_refine<<<128, 128, 0, stream>>>(x, Wl, bl, emb, rcnt, rlist, idxws, out + OUT_OFF_IDX);
    k_out<<<1024, 256, 0, stream>>>(emb, idxws, out + OUT_OFF_OUT, counts);
    k_final<<<1, 256, 0, stream>>>(counts, losssum, out);
}

// Round 3
// 421.934 us; speedup vs baseline: 4.1945x; 1.0754x over previous
//
#include <hip/hip_runtime.h>
#include <hip/hip_bf16.h>
#include <float.h>

// Problem constants
#define NPIX   32768      // B*H*W
#define CDIM   128
#define KCB    8192
#define TAU    0.25f
#define RCAP   8192

typedef _Float16 f16x8 __attribute__((ext_vector_type(8)));
typedef float    f32x16 __attribute__((ext_vector_type(16)));

// ws layout (bytes)
// embF: 256 tiles x 9 steps x 64 lanes x 8 f16 = 2,359,296 B (hi only)
#define WS_EMBFH   0
#define WS_E2      2359296           // 8192 f32
#define WS_IDX     2392064           // 32768 i32
#define WS_RLIST   2523136           // 8192*4 i32
#define WS_COUNTS  2654208           // 8192 f32
#define WS_LOSS    2686976           // 1 f32
#define WS_RCNT    2686980           // 1 i32
#define WS_ZERO_OFF 2654208
#define WS_ZERO_LEN 32776

// d_out layout (f32): [0]=loss, [1..4194304]=out BCHW, [4194305]=perplexity, [4194306..]=idx
#define OUT_OFF_OUT  1
#define OUT_OFF_PERP 4194305
#define OUT_OFF_IDX  4194306

__device__ __forceinline__ void addcand3(float v, int idx,
    float& g1, int& i1, float& g2, int& i2, float& g3, int& i3) {
    if (v < g1) { g3 = g2; i3 = i2; g2 = g1; i2 = i1; g1 = v; i1 = idx; }
    else if (v < g2) { g3 = g2; i3 = i2; g2 = v; i2 = idx; }
    else if (v < g3) { g3 = v; i3 = idx; }
}

// ---------------- K0: e2[k] = sum_c emb[k][c]^2 ----------------
__global__ __launch_bounds__(256) void k_e2(const float* __restrict__ emb, float* __restrict__ e2) {
    int t = threadIdx.x;
    int wv = t >> 6, l = t & 63;
    int k = blockIdx.x * 4 + wv;
    const float2 v = *(const float2*)&emb[(size_t)k * 128 + l * 2];
    float s = v.x * v.x + v.y * v.y;
    #pragma unroll
    for (int o = 32; o; o >>= 1) s += __shfl_down(s, o, 64);
    if (l == 0) e2[k] = s;
}

// ---------------- K1: fragment-ordered -2*emb (f16 hi), with e2 hi/lo fold in step 8 ----------------
// element (g,s,lane,j): code m = g*32 + (lane&31), k-slot = s*16 + (lane>>5)*8 + j
// s<8: value = f16(-2*emb[m][kslot]); s==8, half0: [e2h, 1, 1, e2l, 0,0,0,0]; half1: zeros
__global__ __launch_bounds__(256) void k_prep(const float* __restrict__ emb, const float* __restrict__ e2,
                                              _Float16* __restrict__ embFh) {
    int tid = blockIdx.x * 256 + threadIdx.x;   // < 147456 = 8192*18
    int m = tid / 18, r = tid % 18;
    int s = r >> 1, h = r & 1;
    f16x8 hv;
    #pragma unroll
    for (int j = 0; j < 8; ++j) hv[j] = (_Float16)0.0f;
    if (s < 8) {
        int c0 = s * 16 + h * 8;
        const float4 a = *(const float4*)&emb[(size_t)m * 128 + c0];
        const float4 b = *(const float4*)&emb[(size_t)m * 128 + c0 + 4];
        float vals[8] = {a.x, a.y, a.z, a.w, b.x, b.y, b.z, b.w};
        #pragma unroll
        for (int j = 0; j < 8; ++j) hv[j] = (_Float16)(-2.0f * vals[j]);
    } else if (h == 0) {
        float v = e2[m];
        _Float16 eh = (_Float16)v;
        hv[0] = eh;
        hv[1] = (_Float16)1.0f;   // slot 129: picks up z2h from B
        hv[2] = (_Float16)1.0f;   // slot 130: picks up z2l from B
        hv[3] = (_Float16)(v - (float)eh);  // e2 low part
    }
    size_t base = (((size_t)(m >> 5) * 9 + s) * 64 + (m & 31) + h * 32) * 8;
    *(f16x8*)&embFh[base] = hv;
}

// ---------------- K2: fused linear + MFMA distance + top3 argmin ----------------
// 512 blocks x 256 thr. Block: 64 px (2 tiles of 32). All 4 waves hold both B-tiles;
// wave w processes code-tiles g = w, w+4, ... A streamed from L2 with 1-iter prefetch.
__global__ __launch_bounds__(256, 2) void k_main(
    const float* __restrict__ x, const float* __restrict__ Wl, const float* __restrict__ bl,
    const _Float16* __restrict__ embFh,
    int* __restrict__ idxws, int* __restrict__ rlist, int* __restrict__ rcnt,
    float* __restrict__ losssum, float* __restrict__ out_idxf)
{
    __shared__ __align__(16) float As[64 * 132];   // z [p][c], pitch 132 (33.8 KB)
    __shared__ __align__(16) float Xs[64 * 66];    // x staging / final-merge scratch (16.9 KB)

    const int t  = threadIdx.x;
    const int n0 = blockIdx.x * 64;
    const int b  = n0 >> 10;
    const int hw0 = n0 & 1023;

    // ===== Phase 1: z for 64 pixels =====
    {
        const int p = t & 63, ig = t >> 6;
        float accz[32];
        const float4* bl4 = (const float4*)(bl + ig * 32);
        #pragma unroll
        for (int q = 0; q < 8; ++q) {
            float4 v = bl4[q];
            accz[4*q+0] = v.x; accz[4*q+1] = v.y; accz[4*q+2] = v.z; accz[4*q+3] = v.w;
        }
        for (int half = 0; half < 2; ++half) {
            __syncthreads();
            for (int r = 0; r < 16; ++r) {
                int lin = r * 256 + t;
                int cc = lin >> 6, pp = lin & 63;
                Xs[cc * 66 + pp] = x[(size_t)(b * 128 + half * 64 + cc) * 1024 + hw0 + pp];
            }
            __syncthreads();
            for (int cc4 = 0; cc4 < 16; ++cc4) {
                float xv0 = Xs[(cc4*4+0) * 66 + p];
                float xv1 = Xs[(cc4*4+1) * 66 + p];
                float xv2 = Xs[(cc4*4+2) * 66 + p];
                float xv3 = Xs[(cc4*4+3) * 66 + p];
                #pragma unroll
                for (int ii = 0; ii < 32; ++ii) {
                    const float4 w4 = *(const float4*)&Wl[(size_t)(ig*32+ii) * 128 + half*64 + cc4*4];
                    float a = accz[ii];
                    a = fmaf(w4.x, xv0, a);
                    a = fmaf(w4.y, xv1, a);
                    a = fmaf(w4.z, xv2, a);
                    a = fmaf(w4.w, xv3, a);
                    accz[ii] = a;
                }
            }
        }
        float4* ao = (float4*)&As[p * 132 + ig * 32];
        #pragma unroll
        for (int q = 0; q < 8; ++q)
            ao[q] = make_float4(accz[4*q+0], accz[4*q+1], accz[4*q+2], accz[4*q+3]);
    }
    __syncthreads();

    // ===== Phase 2: B fragments (z hi f16) + z2 hi/lo fold, in registers =====
    const int l = t & 63, w = t >> 6;
    const int half = l >> 5, pcol = l & 31;
    f16x8 B0[9], B1[9];
    #pragma unroll
    for (int nt = 0; nt < 2; ++nt) {
        int p = nt * 32 + pcol;
        float s2 = 0.f;
        #pragma unroll
        for (int s = 0; s < 8; ++s) {
            const float* zp = &As[p * 132 + s * 16 + half * 8];
            float4 v0 = *(const float4*)zp;
            float4 v1 = *(const float4*)(zp + 4);
            float vals[8] = {v0.x, v0.y, v0.z, v0.w, v1.x, v1.y, v1.z, v1.w};
            f16x8 hh;
            #pragma unroll
            for (int j = 0; j < 8; ++j) {
                hh[j] = (_Float16)vals[j];
                s2 = fmaf(vals[j], vals[j], s2);
            }
            if (nt == 0) B0[s] = hh; else B1[s] = hh;
        }
        float s2full = s2 + __shfl_xor(s2, 32, 64);
        f16x8 b8;
        #pragma unroll
        for (int j = 0; j < 8; ++j) b8[j] = (_Float16)0.0f;
        if (half == 0) {
            _Float16 z2h = (_Float16)s2full;
            b8[0] = (_Float16)1.0f;               // slot128: e2h from A
            b8[1] = z2h;                          // slot129: A=1 -> z2h
            b8[2] = (_Float16)(s2full - (float)z2h); // slot130: A=1 -> z2l
            b8[3] = (_Float16)1.0f;               // slot131: e2l from A
        }
        if (nt == 0) B0[8] = b8; else B1[8] = b8;
    }

    // ===== Phase 3: K-loop (no barriers; A direct from L2, 1-iter prefetch) =====
    float gv1[2] = {3e38f, 3e38f}, gv2[2] = {3e38f, 3e38f}, gv3[2] = {3e38f, 3e38f};
    int   gi1[2] = {0, 0},          gi2[2] = {0, 0},          gi3[2] = {0, 0};
    const f16x8* Ahp = (const f16x8*)embFh;
    const int rb4 = half * 4;

    f16x8 a[9];
    {
        const f16x8* P = Ahp + (size_t)w * 9 * 64 + l;
        #pragma unroll
        for (int s = 0; s < 9; ++s) a[s] = P[s * 64];
    }

    for (int g = w; g < 256; g += 4) {
        const int gn = (g + 4 < 256) ? g + 4 : g;
        const f16x8* Pn = Ahp + (size_t)gn * 9 * 64 + l;
        f32x16 acc0 = {}; f32x16 acc1 = {};
        #pragma unroll
        for (int s = 0; s < 9; ++s) {
            f16x8 an = Pn[s * 64];
            acc0 = __builtin_amdgcn_mfma_f32_32x32x16_f16(a[s], B0[s], acc0, 0, 0, 0);
            acc1 = __builtin_amdgcn_mfma_f32_32x32x16_f16(a[s], B1[s], acc1, 0, 0, 0);
            a[s] = an;
        }
        // per-tile packed top-3 (clear low 5 mantissa bits, OR in row idx)
        float m1a = 3e38f, m2a = 3e38f, m3a = 3e38f;
        float m1b = 3e38f, m2b = 3e38f, m3b = 3e38f;
        #pragma unroll
        for (int r = 0; r < 16; ++r) {
            const uint32_t rowc = (uint32_t)((r & 3) + 8 * (r >> 2) + rb4);
            float p0 = __uint_as_float((__float_as_uint(acc0[r]) & 0xFFFFFFE0u) | rowc);
            float t1 = fmaxf(m1a, p0); m1a = fminf(m1a, p0);
            float t2 = fmaxf(m2a, t1); m2a = fminf(m2a, t1);
            m3a = fminf(m3a, t2);
            float p1 = __uint_as_float((__float_as_uint(acc1[r]) & 0xFFFFFFE0u) | rowc);
            float s1 = fmaxf(m1b, p1); m1b = fminf(m1b, p1);
            float s2 = fmaxf(m2b, s1); m2b = fminf(m2b, s1);
            m3b = fminf(m3b, s2);
        }
        const int gbase = g * 32;
        uint32_t u;
        u = __float_as_uint(m1a); addcand3(__uint_as_float(u & 0xFFFFFFE0u), gbase + (int)(u & 31u), gv1[0], gi1[0], gv2[0], gi2[0], gv3[0], gi3[0]);
        u = __float_as_uint(m2a); addcand3(__uint_as_float(u & 0xFFFFFFE0u), gbase + (int)(u & 31u), gv1[0], gi1[0], gv2[0], gi2[0], gv3[0], gi3[0]);
        u = __float_as_uint(m3a); addcand3(__uint_as_float(u & 0xFFFFFFE0u), gbase + (int)(u & 31u), gv1[0], gi1[0], gv2[0], gi2[0], gv3[0], gi3[0]);
        u = __float_as_uint(m1b); addcand3(__uint_as_float(u & 0xFFFFFFE0u), gbase + (int)(u & 31u), gv1[1], gi1[1], gv2[1], gi2[1], gv3[1], gi3[1]);
        u = __float_as_uint(m2b); addcand3(__uint_as_float(u & 0xFFFFFFE0u), gbase + (int)(u & 31u), gv1[1], gi1[1], gv2[1], gi2[1], gv3[1], gi3[1]);
        u = __float_as_uint(m3b); addcand3(__uint_as_float(u & 0xFFFFFFE0u), gbase + (int)(u & 31u), gv1[1], gi1[1], gv2[1], gi2[1], gv3[1], gi3[1]);
    }

    // ===== Phase 4: cross-wave merge per pixel =====
    __syncthreads();
    float2* Ms = (float2*)Xs;   // [64 px][8 slots][3 cand]
    const int slot = w * 2 + half;
    #pragma unroll
    for (int nt = 0; nt < 2; ++nt) {
        int p = nt * 32 + pcol;
        Ms[(p * 8 + slot) * 3 + 0] = make_float2(gv1[nt], __int_as_float(gi1[nt]));
        Ms[(p * 8 + slot) * 3 + 1] = make_float2(gv2[nt], __int_as_float(gi2[nt]));
        Ms[(p * 8 + slot) * 3 + 2] = make_float2(gv3[nt], __int_as_float(gi3[nt]));
    }
    __syncthreads();
    if (t < 64) {
        int n = n0 + t;
        float g1 = 3e38f, g2 = 3e38f, g3 = 3e38f; int j1 = 0, j2 = 0, j3 = 0;
        #pragma unroll
        for (int s = 0; s < 24; ++s) {
            float2 e = Ms[t * 24 + s];
            addcand3(e.x, __float_as_int(e.y), g1, j1, g2, j2, g3, j3);
        }
        idxws[n] = j1;
        out_idxf[n] = (float)j1;
        if (g2 - g1 < TAU) {
            int s = atomicAdd(rcnt, 1);
            if (s < RCAP) { rlist[s*4+0] = n; rlist[s*4+1] = j1; rlist[s*4+2] = j2; rlist[s*4+3] = j3; }
        }
        // loss = 1.25 * sum(d_min) / (N*C)
        float ls = g1;
        #pragma unroll
        for (int o = 32; o; o >>= 1) ls += __shfl_down(ls, o, 64);
        if (t == 0) atomicAdd(losssum, ls);
    }
}

// ---------------- K3: fp64 refinement of near-ties (3 candidates) ----------------
__global__ __launch_bounds__(128) void k_refine(
    const float* __restrict__ x, const float* __restrict__ Wl, const float* __restrict__ bl,
    const float* __restrict__ emb, const int* __restrict__ rcnt, const int* __restrict__ rlist,
    int* __restrict__ idxws, float* __restrict__ out_idxf)
{
    __shared__ double xs[128];
    __shared__ double red[128];
    int cnt = *rcnt; if (cnt > RCAP) cnt = RCAP;
    const int t = threadIdx.x;
    for (int e = blockIdx.x; e < cnt; e += gridDim.x) {
        int n  = rlist[e*4+0];
        int c1 = rlist[e*4+1];
        int c2 = rlist[e*4+2];
        int c3 = rlist[e*4+3];
        int b = n >> 10, hw = n & 1023;
        __syncthreads();
        xs[t] = (double)x[(size_t)(b * 128 + t) * 1024 + hw];
        __syncthreads();
        double z = (double)bl[t];
        for (int c = 0; c < 128; ++c) z += (double)Wl[(size_t)t * 128 + c] * xs[c];
        double d[3]; int cs[3] = {c1, c2, c3};
        #pragma unroll
        for (int q = 0; q < 3; ++q) {
            double da = z - (double)emb[(size_t)cs[q] * 128 + t];
            red[t] = da * da; __syncthreads();
            for (int o = 64; o; o >>= 1) { if (t < o) red[t] += red[t + o]; __syncthreads(); }
            d[q] = red[0]; __syncthreads();
        }
        if (t == 0) {
            int win = c1; double bd = d[0];
            if (d[1] < bd || (d[1] == bd && c2 < win)) { bd = d[1]; win = c2; }
            if (d[2] < bd || (d[2] == bd && c3 < win)) { bd = d[2]; win = c3; }
            idxws[n] = win;
            out_idxf[n] = (float)win;
        }
        __syncthreads();
    }
}

// ---------------- K4: gather + transpose (out == quantized exactly) + histogram ----------------
__global__ __launch_bounds__(256) void k_out(
    const float* __restrict__ emb, const int* __restrict__ idxws,
    float* __restrict__ outp /* d_out + 1 */, float* __restrict__ counts)
{
    __shared__ int is[32];
    const int bid = blockIdx.x;          // 0..1023
    const int b = bid >> 5, h = bid & 31;
    const int nb = b * 1024 + h * 32;
    const int t = threadIdx.x;
    if (t < 32) is[t] = idxws[nb + t];
    __syncthreads();
    const int wcol = t & 31, cg = t >> 5;
    const int id = is[wcol];
    #pragma unroll
    for (int q = 0; q < 4; ++q) {
        int c = cg * 16 + q * 4;
        const float4 v = *(const float4*)&emb[(size_t)id * 128 + c];
        outp[((size_t)(b * 128 + c + 0) * 32 + h) * 32 + wcol] = v.x;
        outp[((size_t)(b * 128 + c + 1) * 32 + h) * 32 + wcol] = v.y;
        outp[((size_t)(b * 128 + c + 2) * 32 + h) * 32 + wcol] = v.z;
        outp[((size_t)(b * 128 + c + 3) * 32 + h) * 32 + wcol] = v.w;
    }
    if (t < 32) atomicAdd(&counts[is[t]], 1.0f);
}

// ---------------- K5: finalize loss + perplexity ----------------
__global__ __launch_bounds__(256) void k_final(
    const float* __restrict__ counts, const float* __restrict__ losssum, float* __restrict__ d_out)
{
    const int t = threadIdx.x;
    float ent = 0.f;
    for (int k = t; k < KCB; k += 256) {
        float p = counts[k] * (1.0f / 32768.0f);
        ent -= p * logf(p + 1e-10f);
    }
    #pragma unroll
    for (int o = 32; o; o >>= 1) ent += __shfl_down(ent, o, 64);
    __shared__ float wred[4];
    if ((t & 63) == 0) wred[t >> 6] = ent;
    __syncthreads();
    if (t == 0) {
        float e = wred[0] + wred[1] + wred[2] + wred[3];
        d_out[0] = 1.25f * (*losssum) * (1.0f / 4194304.0f);
        d_out[OUT_OFF_PERP] = expf(e);
    }
}

extern "C" void kernel_launch(void* const* d_in, const int* in_sizes, int n_in,
                              void* d_out, int out_size, void* d_ws, size_t ws_size,
                              hipStream_t stream) {
    (void)in_sizes; (void)n_in; (void)out_size; (void)ws_size;
    const float* x   = (const float*)d_in[0];
    const float* Wl  = (const float*)d_in[1];
    const float* bl  = (const float*)d_in[2];
    const float* emb = (const float*)d_in[3];
    float* out = (float*)d_out;
    char*  ws  = (char*)d_ws;

    _Float16* embFh = (_Float16*)(ws + WS_EMBFH);
    float* e2      = (float*)(ws + WS_E2);
    int*   idxws   = (int*)  (ws + WS_IDX);
    int*   rlist   = (int*)  (ws + WS_RLIST);
    float* counts  = (float*)(ws + WS_COUNTS);
    float* losssum = (float*)(ws + WS_LOSS);
    int*   rcnt    = (int*)  (ws + WS_RCNT);

    hipMemsetAsync(ws + WS_ZERO_OFF, 0, WS_ZERO_LEN, stream);

    k_e2<<<KCB / 4, 256, 0, stream>>>(emb, e2);
    k_prep<<<576, 256, 0, stream>>>(emb, e2, embFh);
    k_main<<<NPIX / 64, 256, 0, stream>>>(x, Wl, bl, embFh,
                                          idxws, rlist, rcnt, losssum, out + OUT_OFF_IDX);
    k_refine<<<256, 128, 0, stream>>>(x, Wl, bl, emb, rcnt, rlist, idxws, out + OUT_OFF_IDX);
    k_out<<<1024, 256, 0, stream>>>(emb, idxws, out + OUT_OFF_OUT, counts);
    k_final<<<1, 256, 0, stream>>>(counts, losssum, out);
}